// Round 3
// baseline (97.064 us; speedup 1.0000x reference)
//
#include <hip/hip_runtime.h>

#define MDEPTH 5
#define TPB 256
#define LDS_STRIDE 19   // 18 floats/row + 1 pad; lds idx of local float F = F + F/18

__global__ __launch_bounds__(TPB) void memtap_kernel(
    const float* __restrict__ iq, float* __restrict__ out,
    int B, int S, int T)
{
    const int blocksPerB = (T + TPB - 1) / TPB;
    const int b  = blockIdx.x / blocksPerB;
    const int t0 = (blockIdx.x % blocksPerB) * TPB;
    const int tid = threadIdx.x;

    __shared__ float lds[TPB * LDS_STRIDE];

    const int t = t0 + tid;
    if (t < T) {
        const int n = t + MDEPTH;                        // n in [5, S-1]
        const float2* iqb = (const float2*)iq + (size_t)b * S;

        float2 v[MDEPTH + 1];
        #pragma unroll
        for (int k = 0; k <= MDEPTH; ++k) v[k] = iqb[n - k];   // v[k] = iq(n-k)

        float* o = &lds[tid * LDS_STRIDE];
        o[0] = v[0].x;
        o[1] = v[0].y;
        #pragma unroll
        for (int k = 0; k <= MDEPTH; ++k)
            o[2 + k] = sqrtf(v[k].x * v[k].x + v[k].y * v[k].y);
        #pragma unroll
        for (int j = 0; j < MDEPTH; ++j) {
            o[8 + 2 * j] = v[j + 1].x;
            o[9 + 2 * j] = v[j + 1].y;
        }
    }
    __syncthreads();

    // Phase 2: cover the block's contiguous output floats with aligned float4
    // stores. Region base (in floats) mod 4 is 0 or 2 -> shift 0 or 2 floats.
    const int cnt   = min(TPB, T - t0);       // valid rows
    const int nflt  = cnt * 18;               // floats in region (even)
    const size_t baseF = ((size_t)b * T + t0) * 18ull;
    const int shift = (int)(baseF & 3);       // 0 or 2
    const int nq    = (nflt - shift) >> 2;    // float4 body stores
    const int tail  = (nflt - shift) & 3;     // 0 or 2

    float* obase = out + baseF;
    for (int g = tid; g < nq; g += TPB) {
        const unsigned F  = (unsigned)shift + 4u * (unsigned)g;  // local float idx
        const unsigned q  = F / 18u;          // magic-mul
        const unsigned c0 = F - 18u * q;      // col of first float
        const unsigned a0 = F + q;            // lds index of float F
        float4 w;
        w.x = lds[a0];
        w.y = lds[a0 + 1 + (c0 >= 17u)];      // +1 if wrapped into next row
        w.z = lds[a0 + 2 + (c0 >= 16u)];
        w.w = lds[a0 + 3 + (c0 >= 15u)];
        *(float4*)(obase + F) = w;            // (baseF+F)%4==0 -> 16B aligned
    }
    if (tid == 0 && shift) {                  // head 2 floats (row 0, cols 0..1)
        *(float2*)obase = make_float2(lds[0], lds[1]);
    }
    if (tid == 1 && tail) {                   // last 2 floats (row cnt-1, cols 16..17)
        const unsigned F = (unsigned)(nflt - 2);
        const unsigned a = F + F / 18u;
        *(float2*)(obase + F) = make_float2(lds[a], lds[a + 1]);
    }
}

extern "C" void kernel_launch(void* const* d_in, const int* in_sizes, int n_in,
                              void* d_out, int out_size, void* d_ws, size_t ws_size,
                              hipStream_t stream) {
    (void)in_sizes; (void)n_in; (void)d_ws; (void)ws_size; (void)out_size;
    const float* iq = (const float*)d_in[0];
    float* out = (float*)d_out;

    const int B = 64, S = 16384;
    const int T = S - MDEPTH;                     // 16379
    const int blocksPerB = (T + TPB - 1) / TPB;   // 64
    const int grid = B * blocksPerB;              // 4096

    memtap_kernel<<<grid, TPB, 0, stream>>>(iq, out, B, S, T);
}

// Round 4
// 90.280 us; speedup vs baseline: 1.0751x; 1.0751x over previous
//
#include <hip/hip_runtime.h>

#define MDEPTH 5
#define TPB 256

// out[b][t][c], c in 0..17:
//   c 0..1  : iq[b][t+5][c]
//   c 2..7  : sqrt(|iq[b][t+5-(c-2)]|)
//   c 8..17 : iq[b][t+5-1-((c-8)>>1)][(c-8)&1]
__global__ __launch_bounds__(TPB) void memtap_direct(
    const float2* __restrict__ iq2, float4* __restrict__ out4)
{
    constexpr unsigned S = 16384u;
    constexpr unsigned T = 16379u;
    constexpr unsigned RPB = T * 18u;            // floats per batch = 294822
    constexpr unsigned NQ = 64u * RPB / 4u;      // total float4s = 4,717,152

    unsigned g = blockIdx.x * TPB + threadIdx.x;
    const unsigned stride = gridDim.x * TPB;

    for (; g < NQ; g += stride) {
        const unsigned P = 4u * g;               // flat float index
        unsigned b = P / RPB;                    // magic-mul div
        unsigned r = P - b * RPB;
        unsigned t = r / 18u;                    // magic-mul div
        unsigned c = r - 18u * t;                // even (P, RPB, 18 all even)

        float vals[4];
        #pragma unroll
        for (int i = 0; i < 4; ++i) {
            const unsigned n = t + MDEPTH;
            const bool is_env = (c >= 2u) & (c < 8u);
            const unsigned m = (c < 2u) ? n
                             : ((c < 8u) ? (n - (c - 2u))
                                         : (n - 1u - ((c - 8u) >> 1)));
            const unsigned comp = (c < 2u) ? c : ((c - 8u) & 1u);
            const float2 w = iq2[b * S + m];
            const float e  = sqrtf(w.x * w.x + w.y * w.y);
            const float cp = comp ? w.y : w.x;
            vals[i] = is_env ? e : cp;
            // advance one output float (handle row / batch wrap)
            ++c;
            if (c == 18u) { c = 0u; ++t; if (t == T) { t = 0u; ++b; } }
        }
        out4[g] = make_float4(vals[0], vals[1], vals[2], vals[3]);
    }
}

extern "C" void kernel_launch(void* const* d_in, const int* in_sizes, int n_in,
                              void* d_out, int out_size, void* d_ws, size_t ws_size,
                              hipStream_t stream) {
    (void)in_sizes; (void)n_in; (void)d_ws; (void)ws_size; (void)out_size;
    const float2* iq2 = (const float2*)d_in[0];
    float4* out4 = (float4*)d_out;

    const int grid = 4096;   // ~4.5 float4s per thread via grid-stride
    memtap_direct<<<grid, TPB, 0, stream>>>(iq2, out4);
}